// Round 6
// baseline (242.210 us; speedup 1.0000x reference)
//
#include <hip/hip_runtime.h>
#include <stdint.h>

// HyperLatticeBlock: B=2,S=1024,D=1024,L=48,K=4  (tokens T=2048)
// gate(top4)->bucketed single-pass expert GEMM->combine->out_proj->LN
#define TT 2048
#define DD 1024
#define LL 48

typedef __attribute__((ext_vector_type(8))) short short8;
typedef __attribute__((ext_vector_type(4))) float f32x4;

static __device__ __forceinline__ unsigned int f2bf(float f) {
  union { float f; unsigned int u; } v; v.f = f;
  return (v.u + 0x7FFFu + ((v.u >> 16) & 1u)) >> 16;   // RNE f32->bf16 bits
}
static __device__ __forceinline__ unsigned int pack2(float a, float b) {
  return f2bf(a) | (f2bf(b) << 16);
}

typedef __attribute__((address_space(1))) const void* as1_t;
typedef __attribute__((address_space(3))) void* as3_t;
static __device__ __forceinline__ void gll16(const void* g, void* s) {
  __builtin_amdgcn_global_load_lds((as1_t)g, (as3_t)s, 16, 0, 0);
}

// ---------------- gate: logits fp32, top-4, softmax, bucket scatter, x->bf16 ----------------
__global__ __launch_bounds__(256) void k_gate(
    const float* __restrict__ x, const float* __restrict__ gw,
    unsigned short* __restrict__ xb,
    int* __restrict__ counts, int* __restrict__ btok, float* __restrict__ bscore)
{
  __shared__ float xs[8][1024];
  __shared__ float lg[8][48];
  const int tid = threadIdx.x;
  const int t0 = blockIdx.x * 8;
  for (int u = tid; u < 2048; u += 256) {
    int tok = u >> 8;
    int c = (u & 255) << 2;
    float4 v = *(const float4*)(x + (size_t)(t0 + tok) * DD + c);
    *(float4*)&xs[tok][c] = v;
    uint2 p; p.x = pack2(v.x, v.y); p.y = pack2(v.z, v.w);
    *(uint2*)(xb + (size_t)(t0 + tok) * DD + c) = p;
  }
  __syncthreads();
  const int lane = tid & 63, wid = tid >> 6;
  for (int li = 0; li < 12; ++li) {
    const int l = wid + (li << 2);
    const float4* gp = (const float4*)(gw + (size_t)l * DD);
    float4 g0 = gp[lane], g1 = gp[lane + 64], g2 = gp[lane + 128], g3 = gp[lane + 192];
    for (int tok = 0; tok < 8; ++tok) {
      const float4* xp = (const float4*)&xs[tok][0];
      float4 a0 = xp[lane], a1 = xp[lane + 64], a2 = xp[lane + 128], a3 = xp[lane + 192];
      float s = a0.x*g0.x + a0.y*g0.y + a0.z*g0.z + a0.w*g0.w
              + a1.x*g1.x + a1.y*g1.y + a1.z*g1.z + a1.w*g1.w
              + a2.x*g2.x + a2.y*g2.y + a2.z*g2.z + a2.w*g2.w
              + a3.x*g3.x + a3.y*g3.y + a3.z*g3.z + a3.w*g3.w;
      #pragma unroll
      for (int off = 32; off; off >>= 1) s += __shfl_down(s, off);
      if (lane == 0) lg[tok][l] = s;
    }
  }
  __syncthreads();
  if (tid < 8) {
    const int tok = tid;
    float v[4]; int id[4];
    unsigned long long taken = 0ull;
    for (int k = 0; k < 4; ++k) {
      float best = -3.4e38f; int bi = 0;
      for (int l = 0; l < 48; ++l) {
        float cand = lg[tok][l];
        if (!((taken >> l) & 1ull) && cand > best) { best = cand; bi = l; }
      }
      taken |= (1ull << bi); v[k] = best; id[k] = bi;
    }
    float e1 = expf(v[1] - v[0]);
    float e2 = expf(v[2] - v[0]);
    float e3 = expf(v[3] - v[0]);
    float inv = 1.0f / (1.0f + e1 + e2 + e3);
    float sc[4] = { inv, e1*inv, e2*inv, e3*inv };
    for (int k = 0; k < 4; ++k) {
      int pos = atomicAdd(&counts[id[k]], 1);
      btok[id[k] * TT + pos] = ((t0 + tok) << 2) | k;
      bscore[id[k] * TT + pos] = sc[k];
    }
  }
}

// ---------------- expert GEMM: BM=256, BN=64, BK=32, 4 waves (4m x 1n) ----------------
// OUT[t][e] = sum_d X[t][d] * W[l][d][e].
// A: gathered bf16 rows via gll16 -> [256][32] (64B rows).
// B: W fp32 via 2 coalesced float4 -> pack (d,d+1) bf16 pairs -> [64 e][17 u32] rows
//    (17-u32 stride => frag ds_read_b128 exactly 2-way bank = free).
// LDS 43.5KB -> 3 blocks/CU; grid 768 active blocks = 3/CU, 12 waves/CU.
__global__ __launch_bounds__(256, 3) void k_expert(
    const unsigned short* __restrict__ xb, const float* __restrict__ W,
    const int* __restrict__ counts, const int* __restrict__ btok,
    const float* __restrict__ bscore, float* __restrict__ sel)
{
  const int l = blockIdx.z;
  const int ncnt = counts[l];
  const int m0 = blockIdx.y * 256;
  if (m0 >= ncnt) return;
  const int n0 = blockIdx.x * 64;
  const int tid = threadIdx.x, lane = tid & 63, wr = tid >> 6;

  __shared__ alignas(16) unsigned short As[2][256 * 32];  // 16 KB each
  __shared__ alignas(16) unsigned int   Bs[2][64 * 17];   // 4.25 KB each
  __shared__ int   toks[256];
  __shared__ float scs[256];

  {
    int r = m0 + tid;
    toks[tid] = (r < ncnt) ? btok[l * TT + r] : 0;
    scs[tid]  = (r < ncnt) ? bscore[l * TT + r] : 0.f;
  }
  __syncthreads();

  // A staging: unit u = i*256+tid -> row u>>2, 16B slot u&3
  const unsigned short* asrc[4];
  #pragma unroll
  for (int i = 0; i < 4; ++i) {
    int u = i * 256 + tid;
    asrc[i] = xb + (size_t)(toks[u >> 2] >> 2) * DD + (u & 3) * 8;
  }
  // B staging: thread -> d-pair bp (0..15), 4 e's at be0
  const int bp = tid >> 4, be0 = (tid & 15) * 4;
  const float* wsrc0 = W + (size_t)l * DD * DD + (size_t)(2 * bp) * DD + n0 + be0;
  const float* wsrc1 = wsrc0 + DD;

  f32x4 acc[4][4];
  #pragma unroll
  for (int m = 0; m < 4; ++m)
    #pragma unroll
    for (int n = 0; n < 4; ++n)
      #pragma unroll
      for (int j = 0; j < 4; ++j) acc[m][n][j] = 0.f;

  float4 bw0, bw1;

#define BLOAD(k0) do { \
    bw0 = *(const float4*)(wsrc0 + (size_t)(k0) * DD); \
    bw1 = *(const float4*)(wsrc1 + (size_t)(k0) * DD); \
  } while (0)

#define ASTAGE(buf, k0) do { \
    _Pragma("unroll") \
    for (int i = 0; i < 4; ++i) \
      gll16(asrc[i] + (k0), &As[buf][(i * 256 + tid) * 8]); \
  } while (0)

#define BSTORE(buf) do { \
    Bs[buf][(be0 + 0) * 17 + bp] = pack2(bw0.x, bw1.x); \
    Bs[buf][(be0 + 1) * 17 + bp] = pack2(bw0.y, bw1.y); \
    Bs[buf][(be0 + 2) * 17 + bp] = pack2(bw0.z, bw1.z); \
    Bs[buf][(be0 + 3) * 17 + bp] = pack2(bw0.w, bw1.w); \
  } while (0)

  const int fr = lane & 15, fq = lane >> 4;

  BLOAD(0); ASTAGE(0, 0); BSTORE(0);
  __syncthreads();
  int cur = 0;
  for (int t = 0; t < 32; ++t) {
    if (t < 31) { BLOAD((t + 1) * 32); ASTAGE(cur ^ 1, (t + 1) * 32); }
    const unsigned short* Ab = As[cur];
    const unsigned short* Bb = (const unsigned short*)Bs[cur];
    short8 af[4], bf[4];
    #pragma unroll
    for (int m = 0; m < 4; ++m)
      af[m] = *(const short8*)(Ab + (wr * 64 + m * 16 + fr) * 32 + fq * 8);
    #pragma unroll
    for (int n = 0; n < 4; ++n)
      bf[n] = *(const short8*)(Bb + ((n * 16 + fr) * 17 + fq * 4) * 2);
    #pragma unroll
    for (int m = 0; m < 4; ++m)
      #pragma unroll
      for (int n = 0; n < 4; ++n)
        acc[m][n] = __builtin_amdgcn_mfma_f32_16x16x32_bf16(af[m], bf[n], acc[m][n], 0, 0, 0);
    if (t < 31) BSTORE(cur ^ 1);
    __syncthreads();
    cur ^= 1;
  }
#undef BLOAD
#undef ASTAGE
#undef BSTORE

  // epilogue: D[r][c]: c = lane&15 (e), r = (lane>>4)*4 + j  [m89-verified]
  #pragma unroll
  for (int m = 0; m < 4; ++m) {
    #pragma unroll
    for (int j = 0; j < 4; ++j) {
      const int r = wr * 64 + m * 16 + fq * 4 + j;
      if (m0 + r < ncnt) {
        const float sc = scs[r];
        const size_t ob = (size_t)toks[r] * DD + n0 + fr;
        #pragma unroll
        for (int n = 0; n < 4; ++n)
          sel[ob + n * 16] = acc[m][n][j] * sc;
      }
    }
  }
}

// ---------------- combine: lat_bf16[t][d] = sum_k sel[t*4+k][d] ----------------
__global__ __launch_bounds__(256) void k_combine(const float* __restrict__ sel,
                                                 unsigned short* __restrict__ lat)
{
  const size_t i = ((size_t)blockIdx.x * 256 + threadIdx.x) << 2;
  const size_t t = i >> 10, d = i & 1023;
  const float* p = sel + ((t << 2) << 10) + d;
  float4 s0 = *(const float4*)(p);
  float4 s1 = *(const float4*)(p + 1024);
  float4 s2 = *(const float4*)(p + 2048);
  float4 s3 = *(const float4*)(p + 3072);
  float r0 = s0.x + s1.x + s2.x + s3.x;
  float r1 = s0.y + s1.y + s2.y + s3.y;
  float r2 = s0.z + s1.z + s2.z + s3.z;
  float r3 = s0.w + s1.w + s2.w + s3.w;
  uint2 pk; pk.x = pack2(r0, r1); pk.y = pack2(r2, r3);
  *(uint2*)(lat + i) = pk;
}

// ---------------- out_proj: y = x + lat @ out_w^T + b  (BM=128,BN=64, reg-staged dbuf) ----------------
__global__ __launch_bounds__(256, 2) void k_outproj(
    const unsigned short* __restrict__ lat, const float* __restrict__ W2,
    const float* __restrict__ xres, const float* __restrict__ bias,
    float* __restrict__ y)
{
  const int n0 = blockIdx.x * 64;
  const int m0 = blockIdx.y * 128;
  const int tid = threadIdx.x, lane = tid & 63, wid = tid >> 6;

  __shared__ alignas(16) unsigned short As[2][128][40];
  __shared__ alignas(16) unsigned short Bs[2][64][40];

  const int aq = tid >> 2, aseg = tid & 3;
  const unsigned short* la0 = lat + (size_t)(m0 + aq) * DD + aseg * 8;
  const unsigned short* la1 = lat + (size_t)(m0 + aq + 64) * DD + aseg * 8;
  const int be = tid >> 2, bks = tid & 3;
  const float* wb = W2 + (size_t)(n0 + be) * DD + bks * 8;

  f32x4 acc[2][4];
  #pragma unroll
  for (int m = 0; m < 2; ++m)
    #pragma unroll
    for (int n = 0; n < 4; ++n)
      #pragma unroll
      for (int j = 0; j < 4; ++j) acc[m][n][j] = 0.f;

  int4 av0, av1;
  float4 w0, w1;

#define O_LOAD(kk) do { \
    av0 = *(const int4*)(la0 + (kk)); \
    av1 = *(const int4*)(la1 + (kk)); \
    w0 = *(const float4*)(wb + (kk)); \
    w1 = *(const float4*)(wb + (kk) + 4); \
  } while (0)

#define O_STORE(b) do { \
    *(int4*)&As[b][aq][aseg * 8]      = av0; \
    *(int4*)&As[b][aq + 64][aseg * 8] = av1; \
    uint4 pv; \
    pv.x = pack2(w0.x, w0.y); pv.y = pack2(w0.z, w0.w); \
    pv.z = pack2(w1.x, w1.y); pv.w = pack2(w1.z, w1.w); \
    *(uint4*)&Bs[b][be][bks * 8] = pv; \
  } while (0)

  O_LOAD(0); O_STORE(0); __syncthreads();
  int cur = 0;
  for (int t = 0; t < 32; ++t) {
    const bool more = (t < 31);
    if (more) O_LOAD((t + 1) * 32);
    short8 af[2], bf[4];
    #pragma unroll
    for (int n = 0; n < 4; ++n)
      bf[n] = *(const short8*)&Bs[cur][n * 16 + (lane & 15)][(lane >> 4) * 8];
    #pragma unroll
    for (int m = 0; m < 2; ++m)
      af[m] = *(const short8*)&As[cur][wid * 32 + m * 16 + (lane & 15)][(lane >> 4) * 8];
    #pragma unroll
    for (int m = 0; m < 2; ++m)
      #pragma unroll
      for (int n = 0; n < 4; ++n)
        acc[m][n] = __builtin_amdgcn_mfma_f32_16x16x32_bf16(af[m], bf[n], acc[m][n], 0, 0, 0);
    if (more) O_STORE(cur ^ 1);
    __syncthreads();
    cur ^= 1;
  }
#undef O_LOAD
#undef O_STORE

  #pragma unroll
  for (int m = 0; m < 2; ++m) {
    #pragma unroll
    for (int j = 0; j < 4; ++j) {
      const int t = m0 + wid * 32 + m * 16 + ((lane >> 4) << 2) + j;
      #pragma unroll
      for (int n = 0; n < 4; ++n) {
        const int e = n0 + n * 16 + (lane & 15);
        y[(size_t)t * DD + e] = xres[(size_t)t * DD + e] + acc[m][n][j] + bias[e];
      }
    }
  }
}

// ---------------- LayerNorm ----------------
__global__ __launch_bounds__(256) void k_ln(const float* __restrict__ y,
    const float* __restrict__ g, const float* __restrict__ b, float* __restrict__ out)
{
  const int t = blockIdx.x, tid = threadIdx.x;
  float4 v = *(const float4*)(y + (size_t)t * DD + tid * 4);
  float s  = v.x + v.y + v.z + v.w;
  float ss = v.x*v.x + v.y*v.y + v.z*v.z + v.w*v.w;
  #pragma unroll
  for (int off = 32; off; off >>= 1) { s += __shfl_down(s, off); ss += __shfl_down(ss, off); }
  __shared__ float rs[8];
  const int wid = tid >> 6, lane = tid & 63;
  if (lane == 0) { rs[wid] = s; rs[wid + 4] = ss; }
  __syncthreads();
  float S  = rs[0] + rs[1] + rs[2] + rs[3];
  float SS = rs[4] + rs[5] + rs[6] + rs[7];
  float mu = S * (1.0f / DD);
  float var = SS * (1.0f / DD) - mu * mu;
  float inv = rsqrtf(var + 1e-5f);
  float4 gg = *(const float4*)(g + tid * 4);
  float4 bb = *(const float4*)(b + tid * 4);
  float4 o;
  o.x = gg.x * (v.x - mu) * inv + bb.x;
  o.y = gg.y * (v.y - mu) * inv + bb.y;
  o.z = gg.z * (v.z - mu) * inv + bb.z;
  o.w = gg.w * (v.w - mu) * inv + bb.w;
  *(float4*)(out + (size_t)t * DD + tid * 4) = o;
}

extern "C" void kernel_launch(void* const* d_in, const int* in_sizes, int n_in,
                              void* d_out, int out_size, void* d_ws, size_t ws_size,
                              hipStream_t stream) {
  (void)in_sizes; (void)n_in; (void)out_size;
  const float* x   = (const float*)d_in[0];
  const float* gw  = (const float*)d_in[1];
  const float* lw  = (const float*)d_in[2];
  const float* ow  = (const float*)d_in[3];
  const float* obv = (const float*)d_in[4];
  const float* lng = (const float*)d_in[5];
  const float* lnb = (const float*)d_in[6];
  float* out = (float*)d_out;
  char* ws = (char*)d_ws;

  unsigned short* xb     = (unsigned short*)(ws);                          // 4 MB
  unsigned short* lat    = (unsigned short*)(ws + (4ull << 20));           // 4 MB
  float*          y      = (float*)(ws + (8ull << 20));                    // 8 MB
  float*          sel    = (float*)(ws + (16ull << 20));                   // 32 MB
  int*            counts = (int*)(ws + (48ull << 20));                     // 192 B
  int*            btok   = (int*)(ws + (48ull << 20) + 4096);              // 384 KB
  float*          bscore = (float*)(ws + (48ull << 20) + 4096 + (size_t)LL * TT * 4); // 384 KB
  if (ws_size < ((48ull << 20) + 4096 + 2ull * LL * TT * 4)) return;       // loud failure

  hipMemsetAsync(counts, 0, LL * sizeof(int), stream);
  k_gate<<<TT / 8, 256, 0, stream>>>(x, gw, xb, counts, btok, bscore);
  k_expert<<<dim3(16, 2, LL), 256, 0, stream>>>(xb, lw, counts, btok, bscore, sel);
  k_combine<<<TT * DD / (256 * 4), 256, 0, stream>>>(sel, lat);
  k_outproj<<<dim3(16, 16), 256, 0, stream>>>(lat, ow, x, obv, y);
  k_ln<<<TT, 256, 0, stream>>>(y, lng, lnb, out);
}

// Round 7
// 194.118 us; speedup vs baseline: 1.2477x; 1.2477x over previous
//
#include <hip/hip_runtime.h>
#include <stdint.h>

// HyperLatticeBlock: B=2,S=1024,D=1024,L=48,K=4  (tokens T=2048)
// gate(top4)->bucketed single-pass expert GEMM (counted-vmcnt pipeline)->combine->out_proj->LN
#define TT 2048
#define DD 1024
#define LL 48

typedef __attribute__((ext_vector_type(8))) short short8;
typedef __attribute__((ext_vector_type(4))) float f32x4;

static __device__ __forceinline__ unsigned int f2bf(float f) {
  union { float f; unsigned int u; } v; v.f = f;
  return (v.u + 0x7FFFu + ((v.u >> 16) & 1u)) >> 16;   // RNE f32->bf16 bits
}
static __device__ __forceinline__ unsigned int pack2(float a, float b) {
  return f2bf(a) | (f2bf(b) << 16);
}

typedef __attribute__((address_space(1))) const void* as1_t;
typedef __attribute__((address_space(3))) void* as3_t;
static __device__ __forceinline__ void gll16(const void* g, void* s) {
  __builtin_amdgcn_global_load_lds((as1_t)g, (as3_t)s, 16, 0, 0);
}

// ---------------- gate: logits fp32, top-4, softmax, bucket scatter, x->bf16 ----------------
__global__ __launch_bounds__(256) void k_gate(
    const float* __restrict__ x, const float* __restrict__ gw,
    unsigned short* __restrict__ xb,
    int* __restrict__ counts, int* __restrict__ btok, float* __restrict__ bscore)
{
  __shared__ float xs[8][1024];
  __shared__ float lg[8][48];
  const int tid = threadIdx.x;
  const int t0 = blockIdx.x * 8;
  for (int u = tid; u < 2048; u += 256) {
    int tok = u >> 8;
    int c = (u & 255) << 2;
    float4 v = *(const float4*)(x + (size_t)(t0 + tok) * DD + c);
    *(float4*)&xs[tok][c] = v;
    uint2 p; p.x = pack2(v.x, v.y); p.y = pack2(v.z, v.w);
    *(uint2*)(xb + (size_t)(t0 + tok) * DD + c) = p;
  }
  __syncthreads();
  const int lane = tid & 63, wid = tid >> 6;
  for (int li = 0; li < 12; ++li) {
    const int l = wid + (li << 2);
    const float4* gp = (const float4*)(gw + (size_t)l * DD);
    float4 g0 = gp[lane], g1 = gp[lane + 64], g2 = gp[lane + 128], g3 = gp[lane + 192];
    for (int tok = 0; tok < 8; ++tok) {
      const float4* xp = (const float4*)&xs[tok][0];
      float4 a0 = xp[lane], a1 = xp[lane + 64], a2 = xp[lane + 128], a3 = xp[lane + 192];
      float s = a0.x*g0.x + a0.y*g0.y + a0.z*g0.z + a0.w*g0.w
              + a1.x*g1.x + a1.y*g1.y + a1.z*g1.z + a1.w*g1.w
              + a2.x*g2.x + a2.y*g2.y + a2.z*g2.z + a2.w*g2.w
              + a3.x*g3.x + a3.y*g3.y + a3.z*g3.z + a3.w*g3.w;
      #pragma unroll
      for (int off = 32; off; off >>= 1) s += __shfl_down(s, off);
      if (lane == 0) lg[tok][l] = s;
    }
  }
  __syncthreads();
  if (tid < 8) {
    const int tok = tid;
    float v[4]; int id[4];
    unsigned long long taken = 0ull;
    for (int k = 0; k < 4; ++k) {
      float best = -3.4e38f; int bi = 0;
      for (int l = 0; l < 48; ++l) {
        float cand = lg[tok][l];
        if (!((taken >> l) & 1ull) && cand > best) { best = cand; bi = l; }
      }
      taken |= (1ull << bi); v[k] = best; id[k] = bi;
    }
    float e1 = expf(v[1] - v[0]);
    float e2 = expf(v[2] - v[0]);
    float e3 = expf(v[3] - v[0]);
    float inv = 1.0f / (1.0f + e1 + e2 + e3);
    float sc[4] = { inv, e1*inv, e2*inv, e3*inv };
    for (int k = 0; k < 4; ++k) {
      int pos = atomicAdd(&counts[id[k]], 1);
      btok[id[k] * TT + pos] = ((t0 + tok) << 2) | k;
      bscore[id[k] * TT + pos] = sc[k];
    }
  }
}

// ---------------- expert GEMM: BM=256, BN=64, BK=32, 4 waves (4m x 1n) ----------------
// Counted-vmcnt software pipeline (raw s_barrier, never drain to 0 in-loop):
// per iter/thread: BLOAD(t+1)[2 vmem] ; vmcnt(2)=A(t) done ; lgkm(0) ; s_barrier ;
//                  ASTAGE(t+1)[4 gll16] ; compute(t) ; vmcnt(4)=B(t+1) regs ; BSTORE(t+1)
__global__ __launch_bounds__(256, 3) void k_expert(
    const unsigned short* __restrict__ xb, const float* __restrict__ W,
    const int* __restrict__ counts, const int* __restrict__ btok,
    const float* __restrict__ bscore, float* __restrict__ sel)
{
  const int l = blockIdx.z;
  const int ncnt = counts[l];
  const int m0 = blockIdx.y * 256;
  if (m0 >= ncnt) return;
  const int n0 = blockIdx.x * 64;
  const int tid = threadIdx.x, lane = tid & 63, wr = tid >> 6;

  __shared__ alignas(16) unsigned short As[2][256 * 32];  // 16 KB each
  __shared__ alignas(16) unsigned int   Bs[2][64 * 18];   // 4.5 KB each (18-u32 rows: 8B-aligned b64 frags)
  __shared__ int   toks[256];
  __shared__ float scs[256];

  {
    int r = m0 + tid;
    toks[tid] = (r < ncnt) ? btok[l * TT + r] : 0;
    scs[tid]  = (r < ncnt) ? bscore[l * TT + r] : 0.f;
  }
  __syncthreads();   // full drain here (once): establishes vmcnt==0 baseline for the counted pipeline

  // A staging: unit u = i*256+tid -> row u>>2, 16B slot u&3
  const unsigned short* asrc[4];
  #pragma unroll
  for (int i = 0; i < 4; ++i) {
    int u = i * 256 + tid;
    asrc[i] = xb + (size_t)(toks[u >> 2] >> 2) * DD + (u & 3) * 8;
  }
  // B staging: thread -> d-pair bp (0..15), 4 e's at be0
  const int bp = tid >> 4, be0 = (tid & 15) * 4;
  const float* wsrc0 = W + (size_t)l * DD * DD + (size_t)(2 * bp) * DD + n0 + be0;
  const float* wsrc1 = wsrc0 + DD;

  f32x4 acc[4][4];
  #pragma unroll
  for (int m = 0; m < 4; ++m)
    #pragma unroll
    for (int n = 0; n < 4; ++n)
      #pragma unroll
      for (int j = 0; j < 4; ++j) acc[m][n][j] = 0.f;

  float4 bw0, bw1;
  const int fr = lane & 15, fq = lane >> 4;

#define BLOAD(k0) do { \
    bw0 = *(const float4*)(wsrc0 + (size_t)(k0) * DD); \
    bw1 = *(const float4*)(wsrc1 + (size_t)(k0) * DD); \
  } while (0)

#define ASTAGE(buf, k0) do { \
    _Pragma("unroll") \
    for (int i = 0; i < 4; ++i) \
      gll16(asrc[i] + (k0), &As[buf][(i * 256 + tid) * 8]); \
  } while (0)

#define BSTORE(buf) do { \
    Bs[buf][(be0 + 0) * 18 + bp] = pack2(bw0.x, bw1.x); \
    Bs[buf][(be0 + 1) * 18 + bp] = pack2(bw0.y, bw1.y); \
    Bs[buf][(be0 + 2) * 18 + bp] = pack2(bw0.z, bw1.z); \
    Bs[buf][(be0 + 3) * 18 + bp] = pack2(bw0.w, bw1.w); \
  } while (0)

#define COMPUTE(buf) do { \
    const unsigned short* Ab = As[buf]; \
    const unsigned int*   Bb = Bs[buf]; \
    short8 af[4], bf[4]; \
    _Pragma("unroll") \
    for (int m = 0; m < 4; ++m) \
      af[m] = *(const short8*)(Ab + (wr * 64 + m * 16 + fr) * 32 + fq * 8); \
    _Pragma("unroll") \
    for (int n = 0; n < 4; ++n) { \
      uint2 q0 = *(const uint2*)(Bb + (n * 16 + fr) * 18 + fq * 4); \
      uint2 q1 = *(const uint2*)(Bb + (n * 16 + fr) * 18 + fq * 4 + 2); \
      uint4 qq; qq.x = q0.x; qq.y = q0.y; qq.z = q1.x; qq.w = q1.y; \
      bf[n] = *(short8*)&qq; \
    } \
    _Pragma("unroll") \
    for (int m = 0; m < 4; ++m) \
      _Pragma("unroll") \
      for (int n = 0; n < 4; ++n) \
        acc[m][n] = __builtin_amdgcn_mfma_f32_16x16x32_bf16(af[m], bf[n], acc[m][n], 0, 0, 0); \
  } while (0)

#define VM_WAIT(n) do { asm volatile("s_waitcnt vmcnt(" #n ")" ::: "memory"); \
                        __builtin_amdgcn_sched_barrier(0); } while (0)
#define LGKM_WAIT0 do { asm volatile("s_waitcnt lgkmcnt(0)" ::: "memory"); \
                        __builtin_amdgcn_sched_barrier(0); } while (0)

  // prologue: stage tile 0
  BLOAD(0);                     // out: B0:2
  ASTAGE(0, 0);                 // out: B0:2, A0:4
  VM_WAIT(4);                   // B0 regs ready (A0 still in flight)
  BSTORE(0);
  int cur = 0;
  for (int t = 0; t < 31; ++t) {
    BLOAD((t + 1) * 32);        // out: A(t):4 + B(t+1):2
    VM_WAIT(2);                 // A(t) landed in LDS; B(t+1) still flying
    LGKM_WAIT0;                 // our BSTORE ds_writes visible
    __builtin_amdgcn_s_barrier();
    __builtin_amdgcn_sched_barrier(0);
    ASTAGE(cur ^ 1, (t + 1) * 32);  // out: B(t+1):2 + A(t+1):4
    COMPUTE(cur);
    VM_WAIT(4);                 // B(t+1) regs ready
    BSTORE(cur ^ 1);
    cur ^= 1;
  }
  VM_WAIT(0);
  LGKM_WAIT0;
  __builtin_amdgcn_s_barrier();
  __builtin_amdgcn_sched_barrier(0);
  COMPUTE(cur);

#undef BLOAD
#undef ASTAGE
#undef BSTORE
#undef COMPUTE
#undef VM_WAIT
#undef LGKM_WAIT0

  // epilogue: D[r][c]: c = lane&15 (e), r = (lane>>4)*4 + j  [m89-verified]
  #pragma unroll
  for (int m = 0; m < 4; ++m) {
    #pragma unroll
    for (int j = 0; j < 4; ++j) {
      const int r = wr * 64 + m * 16 + fq * 4 + j;
      if (m0 + r < ncnt) {
        const float sc = scs[r];
        const size_t ob = (size_t)toks[r] * DD + n0 + fr;
        #pragma unroll
        for (int n = 0; n < 4; ++n)
          sel[ob + n * 16] = acc[m][n][j] * sc;
      }
    }
  }
}

// ---------------- combine: lat_bf16[t][d] = sum_k sel[t*4+k][d] ----------------
__global__ __launch_bounds__(256) void k_combine(const float* __restrict__ sel,
                                                 unsigned short* __restrict__ lat)
{
  const size_t i = ((size_t)blockIdx.x * 256 + threadIdx.x) << 2;
  const size_t t = i >> 10, d = i & 1023;
  const float* p = sel + ((t << 2) << 10) + d;
  float4 s0 = *(const float4*)(p);
  float4 s1 = *(const float4*)(p + 1024);
  float4 s2 = *(const float4*)(p + 2048);
  float4 s3 = *(const float4*)(p + 3072);
  float r0 = s0.x + s1.x + s2.x + s3.x;
  float r1 = s0.y + s1.y + s2.y + s3.y;
  float r2 = s0.z + s1.z + s2.z + s3.z;
  float r3 = s0.w + s1.w + s2.w + s3.w;
  uint2 pk; pk.x = pack2(r0, r1); pk.y = pack2(r2, r3);
  *(uint2*)(lat + i) = pk;
}

// ---------------- out_proj: y = x + lat @ out_w^T + b  (BM=128,BN=64, reg-staged dbuf) ----------------
__global__ __launch_bounds__(256, 2) void k_outproj(
    const unsigned short* __restrict__ lat, const float* __restrict__ W2,
    const float* __restrict__ xres, const float* __restrict__ bias,
    float* __restrict__ y)
{
  const int n0 = blockIdx.x * 64;
  const int m0 = blockIdx.y * 128;
  const int tid = threadIdx.x, lane = tid & 63, wid = tid >> 6;

  __shared__ alignas(16) unsigned short As[2][128][40];
  __shared__ alignas(16) unsigned short Bs[2][64][40];

  const int aq = tid >> 2, aseg = tid & 3;
  const unsigned short* la0 = lat + (size_t)(m0 + aq) * DD + aseg * 8;
  const unsigned short* la1 = lat + (size_t)(m0 + aq + 64) * DD + aseg * 8;
  const int be = tid >> 2, bks = tid & 3;
  const float* wb = W2 + (size_t)(n0 + be) * DD + bks * 8;

  f32x4 acc[2][4];
  #pragma unroll
  for (int m = 0; m < 2; ++m)
    #pragma unroll
    for (int n = 0; n < 4; ++n)
      #pragma unroll
      for (int j = 0; j < 4; ++j) acc[m][n][j] = 0.f;

  int4 av0, av1;
  float4 w0, w1;

#define O_LOAD(kk) do { \
    av0 = *(const int4*)(la0 + (kk)); \
    av1 = *(const int4*)(la1 + (kk)); \
    w0 = *(const float4*)(wb + (kk)); \
    w1 = *(const float4*)(wb + (kk) + 4); \
  } while (0)

#define O_STORE(b) do { \
    *(int4*)&As[b][aq][aseg * 8]      = av0; \
    *(int4*)&As[b][aq + 64][aseg * 8] = av1; \
    uint4 pv; \
    pv.x = pack2(w0.x, w0.y); pv.y = pack2(w0.z, w0.w); \
    pv.z = pack2(w1.x, w1.y); pv.w = pack2(w1.z, w1.w); \
    *(uint4*)&Bs[b][be][bks * 8] = pv; \
  } while (0)

  O_LOAD(0); O_STORE(0); __syncthreads();
  int cur = 0;
  for (int t = 0; t < 32; ++t) {
    const bool more = (t < 31);
    if (more) O_LOAD((t + 1) * 32);
    short8 af[2], bf[4];
    #pragma unroll
    for (int n = 0; n < 4; ++n)
      bf[n] = *(const short8*)&Bs[cur][n * 16 + (lane & 15)][(lane >> 4) * 8];
    #pragma unroll
    for (int m = 0; m < 2; ++m)
      af[m] = *(const short8*)&As[cur][wid * 32 + m * 16 + (lane & 15)][(lane >> 4) * 8];
    #pragma unroll
    for (int m = 0; m < 2; ++m)
      #pragma unroll
      for (int n = 0; n < 4; ++n)
        acc[m][n] = __builtin_amdgcn_mfma_f32_16x16x32_bf16(af[m], bf[n], acc[m][n], 0, 0, 0);
    if (more) O_STORE(cur ^ 1);
    __syncthreads();
    cur ^= 1;
  }
#undef O_LOAD
#undef O_STORE

  #pragma unroll
  for (int m = 0; m < 2; ++m) {
    #pragma unroll
    for (int j = 0; j < 4; ++j) {
      const int t = m0 + wid * 32 + m * 16 + ((lane >> 4) << 2) + j;
      #pragma unroll
      for (int n = 0; n < 4; ++n) {
        const int e = n0 + n * 16 + (lane & 15);
        y[(size_t)t * DD + e] = xres[(size_t)t * DD + e] + acc[m][n][j] + bias[e];
      }
    }
  }
}

// ---------------- LayerNorm ----------------
__global__ __launch_bounds__(256) void k_ln(const float* __restrict__ y,
    const float* __restrict__ g, const float* __restrict__ b, float* __restrict__ out)
{
  const int t = blockIdx.x, tid = threadIdx.x;
  float4 v = *(const float4*)(y + (size_t)t * DD + tid * 4);
  float s  = v.x + v.y + v.z + v.w;
  float ss = v.x*v.x + v.y*v.y + v.z*v.z + v.w*v.w;
  #pragma unroll
  for (int off = 32; off; off >>= 1) { s += __shfl_down(s, off); ss += __shfl_down(ss, off); }
  __shared__ float rs[8];
  const int wid = tid >> 6, lane = tid & 63;
  if (lane == 0) { rs[wid] = s; rs[wid + 4] = ss; }
  __syncthreads();
  float S  = rs[0] + rs[1] + rs[2] + rs[3];
  float SS = rs[4] + rs[5] + rs[6] + rs[7];
  float mu = S * (1.0f / DD);
  float var = SS * (1.0f / DD) - mu * mu;
  float inv = rsqrtf(var + 1e-5f);
  float4 gg = *(const float4*)(g + tid * 4);
  float4 bb = *(const float4*)(b + tid * 4);
  float4 o;
  o.x = gg.x * (v.x - mu) * inv + bb.x;
  o.y = gg.y * (v.y - mu) * inv + bb.y;
  o.z = gg.z * (v.z - mu) * inv + bb.z;
  o.w = gg.w * (v.w - mu) * inv + bb.w;
  *(float4*)(out + (size_t)t * DD + tid * 4) = o;
}

extern "C" void kernel_launch(void* const* d_in, const int* in_sizes, int n_in,
                              void* d_out, int out_size, void* d_ws, size_t ws_size,
                              hipStream_t stream) {
  (void)in_sizes; (void)n_in; (void)out_size;
  const float* x   = (const float*)d_in[0];
  const float* gw  = (const float*)d_in[1];
  const float* lw  = (const float*)d_in[2];
  const float* ow  = (const float*)d_in[3];
  const float* obv = (const float*)d_in[4];
  const float* lng = (const float*)d_in[5];
  const float* lnb = (const float*)d_in[6];
  float* out = (float*)d_out;
  char* ws = (char*)d_ws;

  unsigned short* xb     = (unsigned short*)(ws);                          // 4 MB
  unsigned short* lat    = (unsigned short*)(ws + (4ull << 20));           // 4 MB
  float*          y      = (float*)(ws + (8ull << 20));                    // 8 MB
  float*          sel    = (float*)(ws + (16ull << 20));                   // 32 MB
  int*            counts = (int*)(ws + (48ull << 20));                     // 192 B
  int*            btok   = (int*)(ws + (48ull << 20) + 4096);              // 384 KB
  float*          bscore = (float*)(ws + (48ull << 20) + 4096 + (size_t)LL * TT * 4); // 384 KB
  if (ws_size < ((48ull << 20) + 4096 + 2ull * LL * TT * 4)) return;       // loud failure

  hipMemsetAsync(counts, 0, LL * sizeof(int), stream);
  k_gate<<<TT / 8, 256, 0, stream>>>(x, gw, xb, counts, btok, bscore);
  k_expert<<<dim3(16, 2, LL), 256, 0, stream>>>(xb, lw, counts, btok, bscore, sel);
  k_combine<<<TT * DD / (256 * 4), 256, 0, stream>>>(sel, lat);
  k_outproj<<<dim3(16, 16), 256, 0, stream>>>(lat, ow, x, obv, y);
  k_ln<<<TT, 256, 0, stream>>>(y, lng, lnb, out);
}

// Round 8
// 193.246 us; speedup vs baseline: 1.2534x; 1.0045x over previous
//
#include <hip/hip_runtime.h>
#include <stdint.h>

// HyperLatticeBlock: B=2,S=1024,D=1024,L=48,K=4  (tokens T=2048)
// gate(top4 + bucket-pack A)->expert GEMM (deep pipeline)->combine(gather)->out_proj->LN
#define TT 2048
#define DD 1024
#define LL 48
#define SENT (LL * 256)   // sentinel selp row (zeroed)

typedef __attribute__((ext_vector_type(8))) short short8;
typedef __attribute__((ext_vector_type(4))) float f32x4;

static __device__ __forceinline__ unsigned int f2bf(float f) {
  union { float f; unsigned int u; } v; v.f = f;
  return (v.u + 0x7FFFu + ((v.u >> 16) & 1u)) >> 16;   // RNE f32->bf16 bits
}
static __device__ __forceinline__ unsigned int pack2(float a, float b) {
  return f2bf(a) | (f2bf(b) << 16);
}

typedef __attribute__((address_space(1))) const void* as1_t;
typedef __attribute__((address_space(3))) void* as3_t;
static __device__ __forceinline__ void gll16(const void* g, void* s) {
  __builtin_amdgcn_global_load_lds((as1_t)g, (as3_t)s, 16, 0, 0);
}

#define VM_WAIT(n) do { asm volatile("s_waitcnt vmcnt(" #n ")" ::: "memory"); \
                        __builtin_amdgcn_sched_barrier(0); } while (0)
#define LGKM0 do { asm volatile("s_waitcnt lgkmcnt(0)" ::: "memory"); \
                   __builtin_amdgcn_sched_barrier(0); } while (0)
#define BAR do { __builtin_amdgcn_s_barrier(); __builtin_amdgcn_sched_barrier(0); } while (0)

// ---------------- gate: logits fp32, top-4, softmax, bucket scatter + A-pack ----------------
__global__ __launch_bounds__(256) void k_gate(
    const float* __restrict__ x, const float* __restrict__ gw,
    unsigned short* __restrict__ xg, int* __restrict__ counts,
    float* __restrict__ bscore, int* __restrict__ tpos)
{
  __shared__ float xs[8][1024];
  __shared__ float lg[8][48];
  __shared__ int tp_s[32];
  const int tid = threadIdx.x;
  const int t0 = blockIdx.x * 8;
  for (int u = tid; u < 2048; u += 256) {
    int tok = u >> 8;
    int c = (u & 255) << 2;
    float4 v = *(const float4*)(x + (size_t)(t0 + tok) * DD + c);
    *(float4*)&xs[tok][c] = v;
  }
  __syncthreads();
  const int lane = tid & 63, wid = tid >> 6;
  for (int li = 0; li < 12; ++li) {
    const int l = wid + (li << 2);
    const float4* gp = (const float4*)(gw + (size_t)l * DD);
    float4 g0 = gp[lane], g1 = gp[lane + 64], g2 = gp[lane + 128], g3 = gp[lane + 192];
    for (int tok = 0; tok < 8; ++tok) {
      const float4* xp = (const float4*)&xs[tok][0];
      float4 a0 = xp[lane], a1 = xp[lane + 64], a2 = xp[lane + 128], a3 = xp[lane + 192];
      float s = a0.x*g0.x + a0.y*g0.y + a0.z*g0.z + a0.w*g0.w
              + a1.x*g1.x + a1.y*g1.y + a1.z*g1.z + a1.w*g1.w
              + a2.x*g2.x + a2.y*g2.y + a2.z*g2.z + a2.w*g2.w
              + a3.x*g3.x + a3.y*g3.y + a3.z*g3.z + a3.w*g3.w;
      #pragma unroll
      for (int off = 32; off; off >>= 1) s += __shfl_down(s, off);
      if (lane == 0) lg[tok][l] = s;
    }
  }
  __syncthreads();
  if (tid < 8) {
    const int tok = tid;
    float v[4]; int id[4];
    unsigned long long taken = 0ull;
    for (int k = 0; k < 4; ++k) {
      float best = -3.4e38f; int bi = 0;
      for (int l = 0; l < 48; ++l) {
        float cand = lg[tok][l];
        if (!((taken >> l) & 1ull) && cand > best) { best = cand; bi = l; }
      }
      taken |= (1ull << bi); v[k] = best; id[k] = bi;
    }
    float e1 = expf(v[1] - v[0]);
    float e2 = expf(v[2] - v[0]);
    float e3 = expf(v[3] - v[0]);
    float inv = 1.0f / (1.0f + e1 + e2 + e3);
    float sc[4] = { inv, e1*inv, e2*inv, e3*inv };
    for (int k = 0; k < 4; ++k) {
      int pos = atomicAdd(&counts[id[k]], 1);
      bscore[id[k] * TT + pos] = sc[k];
      int dst = (pos < 256) ? (id[k] * 256 + pos) : SENT;
      tp_s[tok * 4 + k] = dst;
      tpos[((t0 + tok) << 2) | k] = dst;
    }
  }
  __syncthreads();
  // pack: write each (tok,k)'s bf16 row into its bucket slot (coalesced 2KB rows)
  for (int g = 0; g < 32; ++g) {
    int dst = tp_s[g];
    if (dst == SENT) continue;
    const float* src = xs[g >> 2];
    float a0 = src[tid * 4], a1 = src[tid * 4 + 1], a2 = src[tid * 4 + 2], a3 = src[tid * 4 + 3];
    uint2 pk; pk.x = pack2(a0, a1); pk.y = pack2(a2, a3);
    *(uint2*)(xg + (size_t)dst * DD + tid * 4) = pk;
  }
}

// ---------------- expert GEMM: BM=256, BN=128, BK=32, 512 thr (4m x 2n waves) ----------------
// Deep pipeline: A (contiguous packed bf16) via gll16, triple-buffered, staged 2 iters ahead.
// B (W fp32) reg-staged 3-deep ring -> bf16 pack -> LDS [kpair][132] (b128 write, 2-way b32 read).
// Single counted vmcnt wait per iteration; never drains in-loop.
__global__ __launch_bounds__(512, 1) void k_expert(
    const unsigned short* __restrict__ xg, const float* __restrict__ W,
    const int* __restrict__ counts, const float* __restrict__ bscore,
    float* __restrict__ selp)
{
  const int l = blockIdx.y;
  const int ncnt = min(counts[l], 256);
  const int n0 = blockIdx.x * 128;
  const int tid = threadIdx.x, lane = tid & 63, wid = tid >> 6;
  const int wr = wid & 3, wc = wid >> 2;       // 4m x 2n
  const int fr = lane & 15, fq = lane >> 4;

  __shared__ alignas(16) unsigned short As[3][256 * 32];  // 3 x 16 KB
  __shared__ alignas(16) unsigned int   Bs[2][16 * 132];  // 2 x 8.25 KB
  __shared__ float scs[256];
  if (tid < 256) scs[tid] = (tid < ncnt) ? bscore[l * TT + tid] : 0.f;

  // A: unit u = i*512+tid -> row u>>2, 16B slot u&3 (wave-lane-linear LDS dest)
  const unsigned short* asrc0 = xg + ((size_t)l << 18) + (size_t)(tid >> 2) * DD + (tid & 3) * 8;
  const unsigned short* asrc1 = asrc0 + (size_t)128 * DD;
  // B: thread -> d-pair bp (0..15), 4 e's at e0
  const int bp = tid >> 5, e0 = (tid & 31) << 2;
  const float* wsrc0 = W + (size_t)l * DD * DD + (size_t)(bp << 1) * DD + n0 + e0;
  const float* wsrc1 = wsrc0 + DD;

  f32x4 acc[4][4];
  #pragma unroll
  for (int m = 0; m < 4; ++m)
    #pragma unroll
    for (int n = 0; n < 4; ++n)
      #pragma unroll
      for (int j = 0; j < 4; ++j) acc[m][n][j] = 0.f;

  float4 rw0[3], rw1[3];   // B register ring (indices static after unroll)

#define E_BLOAD(s, k0) do { \
    rw0[s] = *(const float4*)(wsrc0 + (size_t)(k0) * DD); \
    rw1[s] = *(const float4*)(wsrc1 + (size_t)(k0) * DD); } while (0)
#define E_ASTAGE(buf, k0) do { \
    gll16(asrc0 + (k0), &As[buf][tid * 8]); \
    gll16(asrc1 + (k0), &As[buf][(512 + tid) * 8]); } while (0)
#define E_BSTORE(buf, s) do { \
    uint4 pv; \
    pv.x = pack2(rw0[s].x, rw1[s].x); pv.y = pack2(rw0[s].y, rw1[s].y); \
    pv.z = pack2(rw0[s].z, rw1[s].z); pv.w = pack2(rw0[s].w, rw1[s].w); \
    *(uint4*)&Bs[buf][bp * 132 + e0] = pv; } while (0)
#define E_COMPUTE(ab, bb) do { \
    const unsigned short* Ab = As[ab]; const unsigned int* Bb = Bs[bb]; \
    short8 af[4], bf[4]; \
    _Pragma("unroll") for (int m = 0; m < 4; ++m) \
      af[m] = *(const short8*)(Ab + (wr * 64 + m * 16 + fr) * 32 + fq * 8); \
    _Pragma("unroll") for (int n = 0; n < 4; ++n) { \
      const int e = wc * 64 + n * 16 + fr; \
      uint4 q; \
      q.x = Bb[(fq * 4 + 0) * 132 + e]; q.y = Bb[(fq * 4 + 1) * 132 + e]; \
      q.z = Bb[(fq * 4 + 2) * 132 + e]; q.w = Bb[(fq * 4 + 3) * 132 + e]; \
      bf[n] = *(short8*)&q; } \
    _Pragma("unroll") for (int m = 0; m < 4; ++m) \
      _Pragma("unroll") for (int n = 0; n < 4; ++n) \
        acc[m][n] = __builtin_amdgcn_mfma_f32_16x16x32_bf16(af[m], bf[n], acc[m][n], 0, 0, 0); \
  } while (0)

  // ---- prologue: B0,B1,B2 + A0,A1 in flight ----
  E_BLOAD(0, 0); E_BLOAD(1, 32); E_BLOAD(2, 64);
  E_ASTAGE(0, 0); E_ASTAGE(1, 32);
  VM_WAIT(8);                 // B0 regs ready (A0,A1,B1,B2 still flying)
  E_BSTORE(0, 0);
  // ---- t = 0 (peeled: wait(4)) ----
  E_BLOAD(0, 96);             // B3 -> ring slot 0 (B0 consumed)
  VM_WAIT(4);                 // retires B1,B2,A0 -> A0 in LDS, B1 regs ready
  LGKM0; BAR;
  E_ASTAGE(2, 64);            // A2
  E_COMPUTE(0, 0);
  E_BSTORE(1, 1);
  // ---- steady: t = 1..28, single wait(6) ----
  #pragma unroll
  for (int t = 1; t <= 28; ++t) {
    E_BLOAD((t + 3) % 3, (t + 3) * 32);
    VM_WAIT(6);               // retires B(t+1), A(t)
    LGKM0; BAR;
    E_ASTAGE((t + 2) % 3, (t + 2) * 32);
    E_COMPUTE(t % 3, t & 1);
    E_BSTORE((t + 1) & 1, (t + 1) % 3);
  }
  // ---- tail ----
  // t = 29 (no BLOAD): pending {A29,B31,A30}
  VM_WAIT(4);                 // retires A29 (B30 retired at t=28)
  LGKM0; BAR;
  E_ASTAGE(1, 31 * 32);       // A31
  E_COMPUTE(2, 1);
  E_BSTORE(0, 0);             // B30
  // t = 30: pending {B31,A30,A31}
  VM_WAIT(0);                 // A30 + B31 done
  LGKM0; BAR;
  E_COMPUTE(0, 0);
  E_BSTORE(1, 1);             // B31
  // t = 31
  LGKM0; BAR;
  E_COMPUTE(1, 1);

#undef E_BLOAD
#undef E_ASTAGE
#undef E_BSTORE
#undef E_COMPUTE

  // epilogue: D[r][c]: c = lane&15 (e), r = (lane>>4)*4 + j  [m89-verified]
  #pragma unroll
  for (int m = 0; m < 4; ++m) {
    #pragma unroll
    for (int j = 0; j < 4; ++j) {
      const int r = wr * 64 + m * 16 + fq * 4 + j;
      if (r < ncnt) {
        const float sc = scs[r];
        float* op = selp + (size_t)(l * 256 + r) * DD + n0 + wc * 64 + fr;
        #pragma unroll
        for (int n = 0; n < 4; ++n) op[n * 16] = acc[m][n][j] * sc;
      }
    }
  }
}

// ---------------- combine: lat_bf16[t][d] = sum_k selp[tpos[t*4+k]][d] ----------------
__global__ __launch_bounds__(256) void k_combine(const float* __restrict__ selp,
    const int* __restrict__ tpos, unsigned short* __restrict__ lat)
{
  const size_t i = ((size_t)blockIdx.x * 256 + threadIdx.x) << 2;
  const size_t t = i >> 10, d = i & 1023;
  int4 tp = *(const int4*)(tpos + (t << 2));
  float4 s0 = *(const float4*)(selp + (size_t)tp.x * DD + d);
  float4 s1 = *(const float4*)(selp + (size_t)tp.y * DD + d);
  float4 s2 = *(const float4*)(selp + (size_t)tp.z * DD + d);
  float4 s3 = *(const float4*)(selp + (size_t)tp.w * DD + d);
  float r0 = s0.x + s1.x + s2.x + s3.x;
  float r1 = s0.y + s1.y + s2.y + s3.y;
  float r2 = s0.z + s1.z + s2.z + s3.z;
  float r3 = s0.w + s1.w + s2.w + s3.w;
  uint2 pk; pk.x = pack2(r0, r1); pk.y = pack2(r2, r3);
  *(uint2*)(lat + i) = pk;
}

// ---------------- out_proj: y = x + lat @ out_w^T + b  (BM=128,BN=64, reg-staged dbuf) ----------------
__global__ __launch_bounds__(256, 2) void k_outproj(
    const unsigned short* __restrict__ lat, const float* __restrict__ W2,
    const float* __restrict__ xres, const float* __restrict__ bias,
    float* __restrict__ y)
{
  const int n0 = blockIdx.x * 64;
  const int m0 = blockIdx.y * 128;
  const int tid = threadIdx.x, lane = tid & 63, wid = tid >> 6;

  __shared__ alignas(16) unsigned short As[2][128][40];
  __shared__ alignas(16) unsigned short Bs[2][64][40];

  const int aq = tid >> 2, aseg = tid & 3;
  const unsigned short* la0 = lat + (size_t)(m0 + aq) * DD + aseg * 8;
  const unsigned short* la1 = lat + (size_t)(m0 + aq + 64) * DD + aseg * 8;
  const int be = tid >> 2, bks = tid & 3;
  const float* wb = W2 + (size_t)(n0 + be) * DD + bks * 8;

  f32x4 acc[2][4];
  #pragma unroll
  for (int m = 0; m < 2; ++m)
    #pragma unroll
    for (int n = 0; n < 4; ++n)
      #pragma unroll
      for (int j = 0; j < 4; ++j) acc[m][n][j] = 0.f;

  int4 av0, av1;
  float4 w0, w1;

#define O_LOAD(kk) do { \
    av0 = *(const int4*)(la0 + (kk)); \
    av1 = *(const int4*)(la1 + (kk)); \
    w0 = *(const float4*)(wb + (kk)); \
    w1 = *(const float4*)(wb + (kk) + 4); \
  } while (0)

#define O_STORE(b) do { \
    *(int4*)&As[b][aq][aseg * 8]      = av0; \
    *(int4*)&As[b][aq + 64][aseg * 8] = av1; \
    uint4 pv; \
    pv.x = pack2(w0.x, w0.y); pv.y = pack2(w0.z, w0.w); \
    pv.z = pack2(w1.x, w1.y); pv.w = pack2(w1.z, w1.w); \
    *(uint4*)&Bs[b][be][bks * 8] = pv; \
  } while (0)

  O_LOAD(0); O_STORE(0); __syncthreads();
  int cur = 0;
  for (int t = 0; t < 32; ++t) {
    const bool more = (t < 31);
    if (more) O_LOAD((t + 1) * 32);
    short8 af[2], bf[4];
    #pragma unroll
    for (int n = 0; n < 4; ++n)
      bf[n] = *(const short8*)&Bs[cur][n * 16 + (lane & 15)][(lane >> 4) * 8];
    #pragma unroll
    for (int m = 0; m < 2; ++m)
      af[m] = *(const short8*)&As[cur][wid * 32 + m * 16 + (lane & 15)][(lane >> 4) * 8];
    #pragma unroll
    for (int m = 0; m < 2; ++m)
      #pragma unroll
      for (int n = 0; n < 4; ++n)
        acc[m][n] = __builtin_amdgcn_mfma_f32_16x16x32_bf16(af[m], bf[n], acc[m][n], 0, 0, 0);
    if (more) O_STORE(cur ^ 1);
    __syncthreads();
    cur ^= 1;
  }
#undef O_LOAD
#undef O_STORE

  #pragma unroll
  for (int m = 0; m < 2; ++m) {
    #pragma unroll
    for (int j = 0; j < 4; ++j) {
      const int t = m0 + wid * 32 + m * 16 + ((lane >> 4) << 2) + j;
      #pragma unroll
      for (int n = 0; n < 4; ++n) {
        const int e = n0 + n * 16 + (lane & 15);
        y[(size_t)t * DD + e] = xres[(size_t)t * DD + e] + acc[m][n][j] + bias[e];
      }
    }
  }
}

// ---------------- LayerNorm ----------------
__global__ __launch_bounds__(256) void k_ln(const float* __restrict__ y,
    const float* __restrict__ g, const float* __restrict__ b, float* __restrict__ out)
{
  const int t = blockIdx.x, tid = threadIdx.x;
  float4 v = *(const float4*)(y + (size_t)t * DD + tid * 4);
  float s  = v.x + v.y + v.z + v.w;
  float ss = v.x*v.x + v.y*v.y + v.z*v.z + v.w*v.w;
  #pragma unroll
  for (int off = 32; off; off >>= 1) { s += __shfl_down(s, off); ss += __shfl_down(ss, off); }
  __shared__ float rs[8];
  const int wid = tid >> 6, lane = tid & 63;
  if (lane == 0) { rs[wid] = s; rs[wid + 4] = ss; }
  __syncthreads();
  float S  = rs[0] + rs[1] + rs[2] + rs[3];
  float SS = rs[4] + rs[5] + rs[6] + rs[7];
  float mu = S * (1.0f / DD);
  float var = SS * (1.0f / DD) - mu * mu;
  float inv = rsqrtf(var + 1e-5f);
  float4 gg = *(const float4*)(g + tid * 4);
  float4 bb = *(const float4*)(b + tid * 4);
  float4 o;
  o.x = gg.x * (v.x - mu) * inv + bb.x;
  o.y = gg.y * (v.y - mu) * inv + bb.y;
  o.z = gg.z * (v.z - mu) * inv + bb.z;
  o.w = gg.w * (v.w - mu) * inv + bb.w;
  *(float4*)(out + (size_t)t * DD + tid * 4) = o;
}

extern "C" void kernel_launch(void* const* d_in, const int* in_sizes, int n_in,
                              void* d_out, int out_size, void* d_ws, size_t ws_size,
                              hipStream_t stream) {
  (void)in_sizes; (void)n_in; (void)out_size;
  const float* x   = (const float*)d_in[0];
  const float* gw  = (const float*)d_in[1];
  const float* lw  = (const float*)d_in[2];
  const float* ow  = (const float*)d_in[3];
  const float* obv = (const float*)d_in[4];
  const float* lng = (const float*)d_in[5];
  const float* lnb = (const float*)d_in[6];
  float* out = (float*)d_out;
  char* ws = (char*)d_ws;

  // layout (~86.1 MB): xg 24MB | selp 48MB+4KB | lat 4MB | y 8MB | counts | bscore | tpos
  unsigned short* xg     = (unsigned short*)(ws);
  float*          selp   = (float*)(ws + (24ull << 20));
  unsigned short* lat    = (unsigned short*)(ws + (73ull << 20));
  float*          y      = (float*)(ws + (77ull << 20));
  int*            counts = (int*)(ws + (85ull << 20));
  float*          bscore = (float*)(ws + (85ull << 20) + 4096);
  int*            tpos   = (int*)(ws + (86ull << 20));
  if (ws_size < (87ull << 20)) return;   // loud failure (ws observed ~768MB)

  hipMemsetAsync(counts, 0, LL * sizeof(int), stream);
  hipMemsetAsync(selp + (size_t)SENT * DD, 0, DD * sizeof(float), stream);  // sentinel row
  k_gate<<<TT / 8, 256, 0, stream>>>(x, gw, xg, counts, bscore, tpos);
  k_expert<<<dim3(8, LL), 512, 0, stream>>>(xg, lw, counts, bscore, selp);
  k_combine<<<TT * DD / (256 * 4), 256, 0, stream>>>(selp, tpos, lat);
  k_outproj<<<dim3(16, 16), 256, 0, stream>>>(lat, ow, x, obv, y);
  k_ln<<<TT, 256, 0, stream>>>(y, lng, lnb, out);
}

// Round 9
// 191.122 us; speedup vs baseline: 1.2673x; 1.0111x over previous
//
#include <hip/hip_runtime.h>
#include <stdint.h>

// HyperLatticeBlock: B=2,S=1024,D=1024,L=48,K=4  (tokens T=2048)
// gate(top4 + bucket-pack A)->expert GEMM (A-in-reg, B-ring, 1 light barrier/iter)->combine->out_proj->LN
#define TT 2048
#define DD 1024
#define LL 48
#define SENT (LL * 256)   // sentinel selp row (zeroed)

typedef __attribute__((ext_vector_type(8))) short short8;
typedef __attribute__((ext_vector_type(4))) float f32x4;

static __device__ __forceinline__ unsigned int f2bf(float f) {
  union { float f; unsigned int u; } v; v.f = f;
  return (v.u + 0x7FFFu + ((v.u >> 16) & 1u)) >> 16;   // RNE f32->bf16 bits
}
static __device__ __forceinline__ unsigned int pack2(float a, float b) {
  return f2bf(a) | (f2bf(b) << 16);
}

#define LGKM0 do { asm volatile("s_waitcnt lgkmcnt(0)" ::: "memory"); \
                   __builtin_amdgcn_sched_barrier(0); } while (0)
#define BAR do { __builtin_amdgcn_s_barrier(); __builtin_amdgcn_sched_barrier(0); } while (0)

// ---------------- gate: logits fp32, top-4, softmax, bucket scatter + A-pack ----------------
__global__ __launch_bounds__(256) void k_gate(
    const float* __restrict__ x, const float* __restrict__ gw,
    unsigned short* __restrict__ xg, int* __restrict__ counts,
    float* __restrict__ bscore, int* __restrict__ tpos)
{
  __shared__ float xs[8][1024];
  __shared__ float lg[8][48];
  __shared__ int tp_s[32];
  const int tid = threadIdx.x;
  const int t0 = blockIdx.x * 8;
  for (int u = tid; u < 2048; u += 256) {
    int tok = u >> 8;
    int c = (u & 255) << 2;
    float4 v = *(const float4*)(x + (size_t)(t0 + tok) * DD + c);
    *(float4*)&xs[tok][c] = v;
  }
  __syncthreads();
  const int lane = tid & 63, wid = tid >> 6;
  for (int li = 0; li < 12; ++li) {
    const int l = wid + (li << 2);
    const float4* gp = (const float4*)(gw + (size_t)l * DD);
    float4 g0 = gp[lane], g1 = gp[lane + 64], g2 = gp[lane + 128], g3 = gp[lane + 192];
    for (int tok = 0; tok < 8; ++tok) {
      const float4* xp = (const float4*)&xs[tok][0];
      float4 a0 = xp[lane], a1 = xp[lane + 64], a2 = xp[lane + 128], a3 = xp[lane + 192];
      float s = a0.x*g0.x + a0.y*g0.y + a0.z*g0.z + a0.w*g0.w
              + a1.x*g1.x + a1.y*g1.y + a1.z*g1.z + a1.w*g1.w
              + a2.x*g2.x + a2.y*g2.y + a2.z*g2.z + a2.w*g2.w
              + a3.x*g3.x + a3.y*g3.y + a3.z*g3.z + a3.w*g3.w;
      #pragma unroll
      for (int off = 32; off; off >>= 1) s += __shfl_down(s, off);
      if (lane == 0) lg[tok][l] = s;
    }
  }
  __syncthreads();
  if (tid < 8) {
    const int tok = tid;
    float v[4]; int id[4];
    unsigned long long taken = 0ull;
    for (int k = 0; k < 4; ++k) {
      float best = -3.4e38f; int bi = 0;
      for (int l = 0; l < 48; ++l) {
        float cand = lg[tok][l];
        if (!((taken >> l) & 1ull) && cand > best) { best = cand; bi = l; }
      }
      taken |= (1ull << bi); v[k] = best; id[k] = bi;
    }
    float e1 = expf(v[1] - v[0]);
    float e2 = expf(v[2] - v[0]);
    float e3 = expf(v[3] - v[0]);
    float inv = 1.0f / (1.0f + e1 + e2 + e3);
    float sc[4] = { inv, e1*inv, e2*inv, e3*inv };
    for (int k = 0; k < 4; ++k) {
      int pos = atomicAdd(&counts[id[k]], 1);
      bscore[id[k] * TT + pos] = sc[k];
      int dst = (pos < 256) ? (id[k] * 256 + pos) : SENT;
      tp_s[tok * 4 + k] = dst;
      tpos[((t0 + tok) << 2) | k] = dst;
    }
  }
  __syncthreads();
  for (int g = 0; g < 32; ++g) {
    int dst = tp_s[g];
    if (dst == SENT) continue;
    const float* src = xs[g >> 2];
    float a0 = src[tid * 4], a1 = src[tid * 4 + 1], a2 = src[tid * 4 + 2], a3 = src[tid * 4 + 3];
    uint2 pk; pk.x = pack2(a0, a1); pk.y = pack2(a2, a3);
    *(uint2*)(xg + (size_t)dst * DD + tid * 4) = pk;
  }
}

// ---------------- expert GEMM: BM=256, BN=64, BK=32, 256 thr (4m x 1n waves) ----------------
// A: per-wave DIRECT register loads from bucket-contiguous xg (no LDS, no barrier on A),
//    double-buffered 1 iter ahead. Compiler's count-precise waitcnt handles all reg deps.
// B: W fp32 2x float4/thread, 4-deep register ring (2-iter latency cover) -> bf16 pack ->
//    tiny LDS [16 dpair][66 e] dbuf (2-way write / 2-way read = free).
// One lgkm+barrier per iter (B visibility only). 3 blocks/CU, grid 768 = 3/CU exactly.
__global__ __launch_bounds__(256, 3) void k_expert(
    const unsigned short* __restrict__ xg, const float* __restrict__ W,
    const int* __restrict__ counts, const float* __restrict__ bscore,
    float* __restrict__ selp)
{
  const int l = blockIdx.y;
  const int ncnt = min(counts[l], 256);
  const int n0 = blockIdx.x * 64;
  const int tid = threadIdx.x, lane = tid & 63, wr = tid >> 6;
  const int fr = lane & 15, fq = lane >> 4;

  __shared__ alignas(16) unsigned int Bs[2][16 * 66];   // 2 x 4.125 KB
  __shared__ float scs[256];
  scs[tid] = (tid < ncnt) ? bscore[l * TT + tid] : 0.f;

  // A pointers: 4 m-frags, row = wr*64 + m*16 + fr, k-chunk fq*8
  const unsigned short* ap[4];
  #pragma unroll
  for (int m = 0; m < 4; ++m)
    ap[m] = xg + ((size_t)l << 18) + (size_t)(wr * 64 + m * 16 + fr) * DD + fq * 8;
  // B: thread -> d-pair bp (0..15), 4 e's at e0
  const int bp = tid >> 4, e0 = (tid & 15) << 2;
  const float* wsrc0 = W + (size_t)l * DD * DD + (size_t)(bp << 1) * DD + n0 + e0;
  const float* wsrc1 = wsrc0 + DD;

  f32x4 acc[4][4];
  #pragma unroll
  for (int m = 0; m < 4; ++m)
    #pragma unroll
    for (int n = 0; n < 4; ++n)
      #pragma unroll
      for (int j = 0; j < 4; ++j) acc[m][n][j] = 0.f;

  short8 af[2][4];           // A double buffer (parity-indexed, static)
  float4 rw0[4], rw1[4];     // B 4-deep ring (slot-indexed, static)

#define E_BLOAD(s, k0) do { \
    rw0[s] = *(const float4*)(wsrc0 + (size_t)(k0) * DD); \
    rw1[s] = *(const float4*)(wsrc1 + (size_t)(k0) * DD); } while (0)
#define E_ALOAD(p, k0) do { \
    af[p][0] = *(const short8*)(ap[0] + (k0)); \
    af[p][1] = *(const short8*)(ap[1] + (k0)); \
    af[p][2] = *(const short8*)(ap[2] + (k0)); \
    af[p][3] = *(const short8*)(ap[3] + (k0)); } while (0)
#define E_BSTORE(buf, s) do { \
    uint4 pv; \
    pv.x = pack2(rw0[s].x, rw1[s].x); pv.y = pack2(rw0[s].y, rw1[s].y); \
    pv.z = pack2(rw0[s].z, rw1[s].z); pv.w = pack2(rw0[s].w, rw1[s].w); \
    *(uint4*)&Bs[buf][bp * 66 + e0] = pv; } while (0)
#define E_COMPUTE(p) do { \
    const unsigned int* Bb = Bs[p]; \
    short8 bf[4]; \
    _Pragma("unroll") for (int n = 0; n < 4; ++n) { \
      const int e = n * 16 + fr; \
      uint4 q; \
      q.x = Bb[(fq * 4 + 0) * 66 + e]; q.y = Bb[(fq * 4 + 1) * 66 + e]; \
      q.z = Bb[(fq * 4 + 2) * 66 + e]; q.w = Bb[(fq * 4 + 3) * 66 + e]; \
      bf[n] = *(short8*)&q; } \
    _Pragma("unroll") for (int m = 0; m < 4; ++m) \
      _Pragma("unroll") for (int n = 0; n < 4; ++n) \
        acc[m][n] = __builtin_amdgcn_mfma_f32_16x16x32_bf16(af[p][m], bf[n], acc[m][n], 0, 0, 0); \
  } while (0)

// body T: BLOAD B(T+3) slot SL; ALOAD A(T+1) parity PA; lgkm+bar; BSTORE B(T+1)->buf PA slot SS; COMPUTE(T) parity P
#define E_BODY(P, PA, SL, SS, T) do { \
    E_BLOAD(SL, (T + 3) * 32); \
    E_ALOAD(PA, (T + 1) * 32); \
    LGKM0; BAR; \
    E_BSTORE(PA, SS); \
    E_COMPUTE(P); } while (0)

  // prologue: B0,B1,B2 + A0; store B0
  E_BLOAD(0, 0); E_BLOAD(1, 32); E_BLOAD(2, 64);
  E_ALOAD(0, 0);
  E_BSTORE(0, 0);
  for (int t = 0; t < 28; t += 4) {
    E_BODY(0, 1, 3, 1, t + 0);
    E_BODY(1, 0, 0, 2, t + 1);
    E_BODY(0, 1, 1, 3, t + 2);
    E_BODY(1, 0, 2, 0, t + 3);
  }
  E_BODY(0, 1, 3, 1, 28);                 // T=28: B31 -> slot 3
  // T=29 (B-load exhausted; slot load dropped)
  E_ALOAD(0, 30 * 32);
  LGKM0; BAR;
  E_BSTORE(0, 2);                         // B30 (slot 2, loaded T=27)
  E_COMPUTE(1);
  // T=30
  E_ALOAD(1, 31 * 32);
  LGKM0; BAR;
  E_BSTORE(1, 3);                         // B31 (slot 3, loaded T=28)
  E_COMPUTE(0);
  // T=31
  LGKM0; BAR;
  E_COMPUTE(1);

#undef E_BLOAD
#undef E_ALOAD
#undef E_BSTORE
#undef E_COMPUTE
#undef E_BODY

  // epilogue: D[r][c]: c = lane&15 (e), r = (lane>>4)*4 + j  [m89-verified]
  #pragma unroll
  for (int m = 0; m < 4; ++m) {
    #pragma unroll
    for (int j = 0; j < 4; ++j) {
      const int r = wr * 64 + m * 16 + fq * 4 + j;
      if (r < ncnt) {
        const float sc = scs[r];
        float* op = selp + (size_t)(l * 256 + r) * DD + n0 + fr;
        #pragma unroll
        for (int n = 0; n < 4; ++n) op[n * 16] = acc[m][n][j] * sc;
      }
    }
  }
}

// ---------------- combine: lat_bf16[t][d] = sum_k selp[tpos[t*4+k]][d] ----------------
__global__ __launch_bounds__(256) void k_combine(const float* __restrict__ selp,
    const int* __restrict__ tpos, unsigned short* __restrict__ lat)
{
  const size_t i = ((size_t)blockIdx.x * 256 + threadIdx.x) << 2;
  const size_t t = i >> 10, d = i & 1023;
  int4 tp = *(const int4*)(tpos + (t << 2));
  float4 s0 = *(const float4*)(selp + (size_t)tp.x * DD + d);
  float4 s1 = *(const float4*)(selp + (size_t)tp.y * DD + d);
  float4 s2 = *(const float4*)(selp + (size_t)tp.z * DD + d);
  float4 s3 = *(const float4*)(selp + (size_t)tp.w * DD + d);
  float r0 = s0.x + s1.x + s2.x + s3.x;
  float r1 = s0.y + s1.y + s2.y + s3.y;
  float r2 = s0.z + s1.z + s2.z + s3.z;
  float r3 = s0.w + s1.w + s2.w + s3.w;
  uint2 pk; pk.x = pack2(r0, r1); pk.y = pack2(r2, r3);
  *(uint2*)(lat + i) = pk;
}

// ---------------- out_proj: y = x + lat @ out_w^T + b  (BM=128,BN=64, reg-staged dbuf) ----------------
__global__ __launch_bounds__(256, 2) void k_outproj(
    const unsigned short* __restrict__ lat, const float* __restrict__ W2,
    const float* __restrict__ xres, const float* __restrict__ bias,
    float* __restrict__ y)
{
  const int n0 = blockIdx.x * 64;
  const int m0 = blockIdx.y * 128;
  const int tid = threadIdx.x, lane = tid & 63, wid = tid >> 6;

  __shared__ alignas(16) unsigned short As[2][128][40];
  __shared__ alignas(16) unsigned short Bs[2][64][40];

  const int aq = tid >> 2, aseg = tid & 3;
  const unsigned short* la0 = lat + (size_t)(m0 + aq) * DD + aseg * 8;
  const unsigned short* la1 = lat + (size_t)(m0 + aq + 64) * DD + aseg * 8;
  const int be = tid >> 2, bks = tid & 3;
  const float* wb = W2 + (size_t)(n0 + be) * DD + bks * 8;

  f32x4 acc[2][4];
  #pragma unroll
  for (int m = 0; m < 2; ++m)
    #pragma unroll
    for (int n = 0; n < 4; ++n)
      #pragma unroll
      for (int j = 0; j < 4; ++j) acc[m][n][j] = 0.f;

  int4 av0, av1;
  float4 w0, w1;

#define O_LOAD(kk) do { \
    av0 = *(const int4*)(la0 + (kk)); \
    av1 = *(const int4*)(la1 + (kk)); \
    w0 = *(const float4*)(wb + (kk)); \
    w1 = *(const float4*)(wb + (kk) + 4); \
  } while (0)

#define O_STORE(b) do { \
    *(int4*)&As[b][aq][aseg * 8]      = av0; \
    *(int4*)&As[b][aq + 64][aseg * 8] = av1; \
    uint4 pv; \
    pv.x = pack2(w0.x, w0.y); pv.y = pack2(w0.z, w0.w); \
    pv.z = pack2(w1.x, w1.y); pv.w = pack2(w1.z, w1.w); \
    *(uint4*)&Bs[b][be][bks * 8] = pv; \
  } while (0)

  O_LOAD(0); O_STORE(0); __syncthreads();
  int cur = 0;
  for (int t = 0; t < 32; ++t) {
    const bool more = (t < 31);
    if (more) O_LOAD((t + 1) * 32);
    short8 af[2], bf[4];
    #pragma unroll
    for (int n = 0; n < 4; ++n)
      bf[n] = *(const short8*)&Bs[cur][n * 16 + (lane & 15)][(lane >> 4) * 8];
    #pragma unroll
    for (int m = 0; m < 2; ++m)
      af[m] = *(const short8*)&As[cur][wid * 32 + m * 16 + (lane & 15)][(lane >> 4) * 8];
    #pragma unroll
    for (int m = 0; m < 2; ++m)
      #pragma unroll
      for (int n = 0; n < 4; ++n)
        acc[m][n] = __builtin_amdgcn_mfma_f32_16x16x32_bf16(af[m], bf[n], acc[m][n], 0, 0, 0);
    if (more) O_STORE(cur ^ 1);
    __syncthreads();
    cur ^= 1;
  }
#undef O_LOAD
#undef O_STORE

  #pragma unroll
  for (int m = 0; m < 2; ++m) {
    #pragma unroll
    for (int j = 0; j < 4; ++j) {
      const int t = m0 + wid * 32 + m * 16 + ((lane >> 4) << 2) + j;
      #pragma unroll
      for (int n = 0; n < 4; ++n) {
        const int e = n0 + n * 16 + (lane & 15);
        y[(size_t)t * DD + e] = xres[(size_t)t * DD + e] + acc[m][n][j] + bias[e];
      }
    }
  }
}

// ---------------- LayerNorm ----------------
__global__ __launch_bounds__(256) void k_ln(const float* __restrict__ y,
    const float* __restrict__ g, const float* __restrict__ b, float* __restrict__ out)
{
  const int t = blockIdx.x, tid = threadIdx.x;
  float4 v = *(const float4*)(y + (size_t)t * DD + tid * 4);
  float s  = v.x + v.y + v.z + v.w;
  float ss = v.x*v.x + v.y*v.y + v.z*v.z + v.w*v.w;
  #pragma unroll
  for (int off = 32; off; off >>= 1) { s += __shfl_down(s, off); ss += __shfl_down(ss, off); }
  __shared__ float rs[8];
  const int wid = tid >> 6, lane = tid & 63;
  if (lane == 0) { rs[wid] = s; rs[wid + 4] = ss; }
  __syncthreads();
  float S  = rs[0] + rs[1] + rs[2] + rs[3];
  float SS = rs[4] + rs[5] + rs[6] + rs[7];
  float mu = S * (1.0f / DD);
  float var = SS * (1.0f / DD) - mu * mu;
  float inv = rsqrtf(var + 1e-5f);
  float4 gg = *(const float4*)(g + tid * 4);
  float4 bb = *(const float4*)(b + tid * 4);
  float4 o;
  o.x = gg.x * (v.x - mu) * inv + bb.x;
  o.y = gg.y * (v.y - mu) * inv + bb.y;
  o.z = gg.z * (v.z - mu) * inv + bb.z;
  o.w = gg.w * (v.w - mu) * inv + bb.w;
  *(float4*)(out + (size_t)t * DD + tid * 4) = o;
}

extern "C" void kernel_launch(void* const* d_in, const int* in_sizes, int n_in,
                              void* d_out, int out_size, void* d_ws, size_t ws_size,
                              hipStream_t stream) {
  (void)in_sizes; (void)n_in; (void)out_size;
  const float* x   = (const float*)d_in[0];
  const float* gw  = (const float*)d_in[1];
  const float* lw  = (const float*)d_in[2];
  const float* ow  = (const float*)d_in[3];
  const float* obv = (const float*)d_in[4];
  const float* lng = (const float*)d_in[5];
  const float* lnb = (const float*)d_in[6];
  float* out = (float*)d_out;
  char* ws = (char*)d_ws;

  // layout (~86.1 MB): xg 24MB | selp 48MB+4KB | lat 4MB | y 8MB | counts | bscore | tpos
  unsigned short* xg     = (unsigned short*)(ws);
  float*          selp   = (float*)(ws + (24ull << 20));
  unsigned short* lat    = (unsigned short*)(ws + (73ull << 20));
  float*          y      = (float*)(ws + (77ull << 20));
  int*            counts = (int*)(ws + (85ull << 20));
  float*          bscore = (float*)(ws + (85ull << 20) + 4096);
  int*            tpos   = (int*)(ws + (86ull << 20));
  if (ws_size < (87ull << 20)) return;   // loud failure

  hipMemsetAsync(counts, 0, LL * sizeof(int), stream);
  hipMemsetAsync(selp + (size_t)SENT * DD, 0, DD * sizeof(float), stream);  // sentinel row
  k_gate<<<TT / 8, 256, 0, stream>>>(x, gw, xg, counts, bscore, tpos);
  k_expert<<<dim3(16, LL), 256, 0, stream>>>(xg, lw, counts, bscore, selp);
  k_combine<<<TT * DD / (256 * 4), 256, 0, stream>>>(selp, tpos, lat);
  k_outproj<<<dim3(16, 16), 256, 0, stream>>>(lat, ow, x, obv, y);
  k_ln<<<TT, 256, 0, stream>>>(y, lng, lnb, out);
}

// Round 10
// 183.009 us; speedup vs baseline: 1.3235x; 1.0443x over previous
//
#include <hip/hip_runtime.h>
#include <stdint.h>

// HyperLatticeBlock: B=2,S=1024,D=1024,L=48,K=4  (tokens T=2048)
// gate(top4 + bucket-pack A)->expert GEMM (BN=256, XCD-chunked, A-in-reg)->combine->out_proj->LN
#define TT 2048
#define DD 1024
#define LL 48
#define SENT (LL * 256)   // sentinel selp row (zeroed)

typedef __attribute__((ext_vector_type(8))) short short8;
typedef __attribute__((ext_vector_type(4))) float f32x4;

static __device__ __forceinline__ unsigned int f2bf(float f) {
  union { float f; unsigned int u; } v; v.f = f;
  return (v.u + 0x7FFFu + ((v.u >> 16) & 1u)) >> 16;   // RNE f32->bf16 bits
}
static __device__ __forceinline__ unsigned int pack2(float a, float b) {
  return f2bf(a) | (f2bf(b) << 16);
}

#define LGKM0 do { asm volatile("s_waitcnt lgkmcnt(0)" ::: "memory"); \
                   __builtin_amdgcn_sched_barrier(0); } while (0)
#define BAR do { __builtin_amdgcn_s_barrier(); __builtin_amdgcn_sched_barrier(0); } while (0)

// ---------------- gate: logits fp32, top-4, softmax, bucket scatter + A-pack ----------------
__global__ __launch_bounds__(256) void k_gate(
    const float* __restrict__ x, const float* __restrict__ gw,
    unsigned short* __restrict__ xg, int* __restrict__ counts,
    float* __restrict__ bscore, int* __restrict__ tpos)
{
  __shared__ float xs[8][1024];
  __shared__ float lg[8][48];
  __shared__ int tp_s[32];
  const int tid = threadIdx.x;
  const int t0 = blockIdx.x * 8;
  for (int u = tid; u < 2048; u += 256) {
    int tok = u >> 8;
    int c = (u & 255) << 2;
    float4 v = *(const float4*)(x + (size_t)(t0 + tok) * DD + c);
    *(float4*)&xs[tok][c] = v;
  }
  __syncthreads();
  const int lane = tid & 63, wid = tid >> 6;
  for (int li = 0; li < 12; ++li) {
    const int l = wid + (li << 2);
    const float4* gp = (const float4*)(gw + (size_t)l * DD);
    float4 g0 = gp[lane], g1 = gp[lane + 64], g2 = gp[lane + 128], g3 = gp[lane + 192];
    for (int tok = 0; tok < 8; ++tok) {
      const float4* xp = (const float4*)&xs[tok][0];
      float4 a0 = xp[lane], a1 = xp[lane + 64], a2 = xp[lane + 128], a3 = xp[lane + 192];
      float s = a0.x*g0.x + a0.y*g0.y + a0.z*g0.z + a0.w*g0.w
              + a1.x*g1.x + a1.y*g1.y + a1.z*g1.z + a1.w*g1.w
              + a2.x*g2.x + a2.y*g2.y + a2.z*g2.z + a2.w*g2.w
              + a3.x*g3.x + a3.y*g3.y + a3.z*g3.z + a3.w*g3.w;
      #pragma unroll
      for (int off = 32; off; off >>= 1) s += __shfl_down(s, off);
      if (lane == 0) lg[tok][l] = s;
    }
  }
  __syncthreads();
  if (tid < 8) {
    const int tok = tid;
    float v[4]; int id[4];
    unsigned long long taken = 0ull;
    for (int k = 0; k < 4; ++k) {
      float best = -3.4e38f; int bi = 0;
      for (int l = 0; l < 48; ++l) {
        float cand = lg[tok][l];
        if (!((taken >> l) & 1ull) && cand > best) { best = cand; bi = l; }
      }
      taken |= (1ull << bi); v[k] = best; id[k] = bi;
    }
    float e1 = expf(v[1] - v[0]);
    float e2 = expf(v[2] - v[0]);
    float e3 = expf(v[3] - v[0]);
    float inv = 1.0f / (1.0f + e1 + e2 + e3);
    float sc[4] = { inv, e1*inv, e2*inv, e3*inv };
    for (int k = 0; k < 4; ++k) {
      int pos = atomicAdd(&counts[id[k]], 1);
      bscore[id[k] * TT + pos] = sc[k];
      int dst = (pos < 256) ? (id[k] * 256 + pos) : SENT;
      tp_s[tok * 4 + k] = dst;
      tpos[((t0 + tok) << 2) | k] = dst;
    }
  }
  __syncthreads();
  for (int g = 0; g < 32; ++g) {
    int dst = tp_s[g];
    if (dst == SENT) continue;
    const float* src = xs[g >> 2];
    float a0 = src[tid * 4], a1 = src[tid * 4 + 1], a2 = src[tid * 4 + 2], a3 = src[tid * 4 + 3];
    uint2 pk; pk.x = pack2(a0, a1); pk.y = pack2(a2, a3);
    *(uint2*)(xg + (size_t)dst * DD + tid * 4) = pk;
  }
}

// ---------------- expert GEMM: BM=256, BN=256, BK=32, 512 thr (4m x 2n waves) ----------------
// Traffic-minimized: A re-read x4 (was x16), W once => 288 MB total.
// Grid flat 192: l = bid%48, nt = bid/48 -> an expert's 4 blocks share an XCD (bid%8),
// so A re-reads hit that XCD's L2 (6 experts x 512KB = 3MB < 4MB L2).
// A: per-wave direct register loads (dbuf). B: fp32 2-deep reg ring -> bf16 -> LDS [16][264] dbuf.
__global__ __launch_bounds__(512, 1) void k_expert(
    const unsigned short* __restrict__ xg, const float* __restrict__ W,
    const int* __restrict__ counts, const float* __restrict__ bscore,
    float* __restrict__ selp)
{
  const int bid = blockIdx.x;
  const int l = bid % LL;
  const int n0 = (bid / LL) * 256;
  const int ncnt = min(counts[l], 256);
  const int tid = threadIdx.x, lane = tid & 63, wid = tid >> 6;
  const int wr = wid & 3, wc = wid >> 2;       // 4m x 2n (wave tile 64 x 128)
  const int fr = lane & 15, fq = lane >> 4;

  __shared__ alignas(16) unsigned int Bs[2][16 * 264];   // 2 x 16.5 KB
  __shared__ float scs[256];
  if (tid < 256) scs[tid] = (tid < ncnt) ? bscore[l * TT + tid] : 0.f;

  // A pointers: 4 m-frags, row = wr*64 + m*16 + fr, k-chunk fq*8
  const unsigned short* ap[4];
  #pragma unroll
  for (int m = 0; m < 4; ++m)
    ap[m] = xg + ((size_t)l << 18) + (size_t)(wr * 64 + m * 16 + fr) * DD + fq * 8;
  // B: thread -> d-pair bp (0..15), 8 e's at e0
  const int bp = tid >> 5, e0 = (tid & 31) << 3;
  const float* wsrc0 = W + (size_t)l * DD * DD + (size_t)(bp << 1) * DD + n0 + e0;
  const float* wsrc1 = wsrc0 + DD;

  f32x4 acc[4][8];
  #pragma unroll
  for (int m = 0; m < 4; ++m)
    #pragma unroll
    for (int n = 0; n < 8; ++n)
      #pragma unroll
      for (int j = 0; j < 4; ++j) acc[m][n][j] = 0.f;

  short8 af[2][4];               // A double buffer (parity-indexed)
  float4 rw[2][4];               // B 2-deep ring (slot-indexed)

#define E_BLOAD(s, k0) do { \
    rw[s][0] = *(const float4*)(wsrc0 + (size_t)(k0) * DD); \
    rw[s][1] = *(const float4*)(wsrc0 + (size_t)(k0) * DD + 4); \
    rw[s][2] = *(const float4*)(wsrc1 + (size_t)(k0) * DD); \
    rw[s][3] = *(const float4*)(wsrc1 + (size_t)(k0) * DD + 4); } while (0)
#define E_ALOAD(p, k0) do { \
    af[p][0] = *(const short8*)(ap[0] + (k0)); \
    af[p][1] = *(const short8*)(ap[1] + (k0)); \
    af[p][2] = *(const short8*)(ap[2] + (k0)); \
    af[p][3] = *(const short8*)(ap[3] + (k0)); } while (0)
#define E_BSTORE(buf, s) do { \
    uint4 p0, p1; \
    p0.x = pack2(rw[s][0].x, rw[s][2].x); p0.y = pack2(rw[s][0].y, rw[s][2].y); \
    p0.z = pack2(rw[s][0].z, rw[s][2].z); p0.w = pack2(rw[s][0].w, rw[s][2].w); \
    p1.x = pack2(rw[s][1].x, rw[s][3].x); p1.y = pack2(rw[s][1].y, rw[s][3].y); \
    p1.z = pack2(rw[s][1].z, rw[s][3].z); p1.w = pack2(rw[s][1].w, rw[s][3].w); \
    *(uint4*)&Bs[buf][bp * 264 + e0]     = p0; \
    *(uint4*)&Bs[buf][bp * 264 + e0 + 4] = p1; } while (0)
#define E_COMPUTE(buf, p) do { \
    const unsigned int* Bb = Bs[buf]; \
    _Pragma("unroll") for (int n = 0; n < 8; ++n) { \
      const int e = wc * 128 + n * 16 + fr; \
      uint4 q; \
      q.x = Bb[(fq * 4 + 0) * 264 + e]; q.y = Bb[(fq * 4 + 1) * 264 + e]; \
      q.z = Bb[(fq * 4 + 2) * 264 + e]; q.w = Bb[(fq * 4 + 3) * 264 + e]; \
      short8 bf = *(short8*)&q; \
      _Pragma("unroll") for (int m = 0; m < 4; ++m) \
        acc[m][n] = __builtin_amdgcn_mfma_f32_16x16x32_bf16(af[p][m], bf, acc[m][n], 0, 0, 0); \
    } } while (0)

  // prologue: B0->slot0, B1->slot1, A0->p0; store B0 into LDS buf0
  E_BLOAD(0, 0); E_BLOAD(1, 32);
  E_ALOAD(0, 0);
  E_BSTORE(0, 0);
  LGKM0; BAR;
  // steady: t = 0..29 (2-step body; BLOAD(t) fetches B(t+2))
  for (int t = 0; t < 30; t += 2) {
    // t even (parity 0)
    E_BLOAD(0, (t + 2) * 32);
    E_ALOAD(1, (t + 1) * 32);
    E_COMPUTE(0, 0);
    LGKM0; BAR;
    E_BSTORE(1, 1);
    LGKM0; BAR;
    // t+1 (parity 1)
    E_BLOAD(1, (t + 3) * 32);
    E_ALOAD(0, (t + 2) * 32);
    E_COMPUTE(1, 1);
    LGKM0; BAR;
    E_BSTORE(0, 0);
    LGKM0; BAR;
  }
  // t = 30 (parity 0): no BLOAD (B31 already in slot1)
  E_ALOAD(1, 31 * 32);
  E_COMPUTE(0, 0);
  LGKM0; BAR;
  E_BSTORE(1, 1);
  LGKM0; BAR;
  // t = 31 (parity 1)
  E_COMPUTE(1, 1);

#undef E_BLOAD
#undef E_ALOAD
#undef E_BSTORE
#undef E_COMPUTE

  // epilogue: D[r][c]: c = lane&15 (e), r = (lane>>4)*4 + j  [m89-verified]
  #pragma unroll
  for (int m = 0; m < 4; ++m) {
    #pragma unroll
    for (int j = 0; j < 4; ++j) {
      const int r = wr * 64 + m * 16 + fq * 4 + j;
      if (r < ncnt) {
        const float sc = scs[r];
        float* op = selp + (size_t)(l * 256 + r) * DD + n0 + wc * 128 + fr;
        #pragma unroll
        for (int n = 0; n < 8; ++n) op[n * 16] = acc[m][n][j] * sc;
      }
    }
  }
}

// ---------------- combine: lat_bf16[t][d] = sum_k selp[tpos[t*4+k]][d] ----------------
__global__ __launch_bounds__(256) void k_combine(const float* __restrict__ selp,
    const int* __restrict__ tpos, unsigned short* __restrict__ lat)
{
  const size_t i = ((size_t)blockIdx.x * 256 + threadIdx.x) << 2;
  const size_t t = i >> 10, d = i & 1023;
  int4 tp = *(const int4*)(tpos + (t << 2));
  float4 s0 = *(const float4*)(selp + (size_t)tp.x * DD + d);
  float4 s1 = *(const float4*)(selp + (size_t)tp.y * DD + d);
  float4 s2 = *(const float4*)(selp + (size_t)tp.z * DD + d);
  float4 s3 = *(const float4*)(selp + (size_t)tp.w * DD + d);
  float r0 = s0.x + s1.x + s2.x + s3.x;
  float r1 = s0.y + s1.y + s2.y + s3.y;
  float r2 = s0.z + s1.z + s2.z + s3.z;
  float r3 = s0.w + s1.w + s2.w + s3.w;
  uint2 pk; pk.x = pack2(r0, r1); pk.y = pack2(r2, r3);
  *(uint2*)(lat + i) = pk;
}

// ---------------- out_proj: y = x + lat @ out_w^T + b  (BM=128,BN=64, reg-staged dbuf) ----------------
__global__ __launch_bounds__(256, 2) void k_outproj(
    const unsigned short* __restrict__ lat, const float* __restrict__ W2,
    const float* __restrict__ xres, const float* __restrict__ bias,
    float* __restrict__ y)
{
  const int n0 = blockIdx.x * 64;
  const int m0 = blockIdx.y * 128;
  const int tid = threadIdx.x, lane = tid & 63, wid = tid >> 6;

  __shared__ alignas(16) unsigned short As[2][128][40];
  __shared__ alignas(16) unsigned short Bs[2][64][40];

  const int aq = tid >> 2, aseg = tid & 3;
  const unsigned short* la0 = lat + (size_t)(m0 + aq) * DD + aseg * 8;
  const unsigned short* la1 = lat + (size_t)(m0 + aq + 64) * DD + aseg * 8;
  const int be = tid >> 2, bks = tid & 3;
  const float* wb = W2 + (size_t)(n0 + be) * DD + bks * 8;

  f32x4 acc[2][4];
  #pragma unroll
  for (int m = 0; m < 2; ++m)
    #pragma unroll
    for (int n = 0; n < 4; ++n)
      #pragma unroll
      for (int j = 0; j < 4; ++j) acc[m][n][j] = 0.f;

  int4 av0, av1;
  float4 w0, w1;

#define O_LOAD(kk) do { \
    av0 = *(const int4*)(la0 + (kk)); \
    av1 = *(const int4*)(la1 + (kk)); \
    w0 = *(const float4*)(wb + (kk)); \
    w1 = *(const float4*)(wb + (kk) + 4); \
  } while (0)

#define O_STORE(b) do { \
    *(int4*)&As[b][aq][aseg * 8]      = av0; \
    *(int4*)&As[b][aq + 64][aseg * 8] = av1; \
    uint4 pv; \
    pv.x = pack2(w0.x, w0.y); pv.y = pack2(w0.z, w0.w); \
    pv.z = pack2(w1.x, w1.y); pv.w = pack2(w1.z, w1.w); \
    *(uint4*)&Bs[b][be][bks * 8] = pv; \
  } while (0)

  O_LOAD(0); O_STORE(0); __syncthreads();
  int cur = 0;
  for (int t = 0; t < 32; ++t) {
    const bool more = (t < 31);
    if (more) O_LOAD((t + 1) * 32);
    short8 af[2], bf[4];
    #pragma unroll
    for (int n = 0; n < 4; ++n)
      bf[n] = *(const short8*)&Bs[cur][n * 16 + (lane & 15)][(lane >> 4) * 8];
    #pragma unroll
    for (int m = 0; m < 2; ++m)
      af[m] = *(const short8*)&As[cur][wid * 32 + m * 16 + (lane & 15)][(lane >> 4) * 8];
    #pragma unroll
    for (int m = 0; m < 2; ++m)
      #pragma unroll
      for (int n = 0; n < 4; ++n)
        acc[m][n] = __builtin_amdgcn_mfma_f32_16x16x32_bf16(af[m], bf[n], acc[m][n], 0, 0, 0);
    if (more) O_STORE(cur ^ 1);
    __syncthreads();
    cur ^= 1;
  }
#undef O_LOAD
#undef O_STORE

  #pragma unroll
  for (int m = 0; m < 2; ++m) {
    #pragma unroll
    for (int j = 0; j < 4; ++j) {
      const int t = m0 + wid * 32 + m * 16 + ((lane >> 4) << 2) + j;
      #pragma unroll
      for (int n = 0; n < 4; ++n) {
        const int e = n0 + n * 16 + (lane & 15);
        y[(size_t)t * DD + e] = xres[(size_t)t * DD + e] + acc[m][n][j] + bias[e];
      }
    }
  }
}

// ---------------- LayerNorm ----------------
__global__ __launch_bounds__(256) void k_ln(const float* __restrict__ y,
    const float* __restrict__ g, const float* __restrict__ b, float* __restrict__ out)
{
  const int t = blockIdx.x, tid = threadIdx.x;
  float4 v = *(const float4*)(y + (size_t)t * DD + tid * 4);
  float s  = v.x + v.y + v.z + v.w;
  float ss = v.x*v.x + v.y*v.y + v.z*v.z + v.w*v.w;
  #pragma unroll
  for (int off = 32; off; off >>= 1) { s += __shfl_down(s, off); ss += __shfl_down(ss, off); }
  __shared__ float rs[8];
  const int wid = tid >> 6, lane = tid & 63;
  if (lane == 0) { rs[wid] = s; rs[wid + 4] = ss; }
  __syncthreads();
  float S  = rs[0] + rs[1] + rs[2] + rs[3];
  float SS = rs[4] + rs[5] + rs[6] + rs[7];
  float mu = S * (1.0f / DD);
  float var = SS * (1.0f / DD) - mu * mu;
  float inv = rsqrtf(var + 1e-5f);
  float4 gg = *(const float4*)(g + tid * 4);
  float4 bb = *(const float4*)(b + tid * 4);
  float4 o;
  o.x = gg.x * (v.x - mu) * inv + bb.x;
  o.y = gg.y * (v.y - mu) * inv + bb.y;
  o.z = gg.z * (v.z - mu) * inv + bb.z;
  o.w = gg.w * (v.w - mu) * inv + bb.w;
  *(float4*)(out + (size_t)t * DD + tid * 4) = o;
}

extern "C" void kernel_launch(void* const* d_in, const int* in_sizes, int n_in,
                              void* d_out, int out_size, void* d_ws, size_t ws_size,
                              hipStream_t stream) {
  (void)in_sizes; (void)n_in; (void)out_size;
  const float* x   = (const float*)d_in[0];
  const float* gw  = (const float*)d_in[1];
  const float* lw  = (const float*)d_in[2];
  const float* ow  = (const float*)d_in[3];
  const float* obv = (const float*)d_in[4];
  const float* lng = (const float*)d_in[5];
  const float* lnb = (const float*)d_in[6];
  float* out = (float*)d_out;
  char* ws = (char*)d_ws;

  // layout (~86.1 MB): xg 24MB | selp 48MB+4KB | lat 4MB | y 8MB | counts | bscore | tpos
  unsigned short* xg     = (unsigned short*)(ws);
  float*          selp   = (float*)(ws + (24ull << 20));
  unsigned short* lat    = (unsigned short*)(ws + (73ull << 20));
  float*          y      = (float*)(ws + (77ull << 20));
  int*            counts = (int*)(ws + (85ull << 20));
  float*          bscore = (float*)(ws + (85ull << 20) + 4096);
  int*            tpos   = (int*)(ws + (86ull << 20));
  if (ws_size < (87ull << 20)) return;   // loud failure

  hipMemsetAsync(counts, 0, LL * sizeof(int), stream);
  hipMemsetAsync(selp + (size_t)SENT * DD, 0, DD * sizeof(float), stream);  // sentinel row
  k_gate<<<TT / 8, 256, 0, stream>>>(x, gw, xg, counts, bscore, tpos);
  k_expert<<<192, 512, 0, stream>>>(xg, lw, counts, bscore, selp);
  k_combine<<<TT * DD / (256 * 4), 256, 0, stream>>>(selp, tpos, lat);
  k_outproj<<<dim3(16, 16), 256, 0, stream>>>(lat, ow, x, obv, y);
  k_ln<<<TT, 256, 0, stream>>>(y, lng, lnb, out);
}